// Round 1
// 68.982 us; speedup vs baseline: 1.0267x; 1.0267x over previous
//
#include <hip/hip_runtime.h>
#include <math.h>
#include <limits.h>

#define NUM_CLS   80
#define MAX_BOXES 128
#define NLVL      5
#define BIG_AREA  1.0e7f
#define TOTAL_PIX 34100
#define PPB       128          // pixels per block in gather

// __float_as_uint(1e7f) == 0x4B189680 ; untouched pixels keep this key (idx 0).
// Any real in-box area <= 1280*1280 = 1.64e6 < 1e7, so touched keys are strictly smaller.
#define INIT_KEY  0x4B18968000000000ULL

// level pixel-offsets: L0 160^2=25600, L1 80^2=6400, L2 40^2=1600, L3 20^2=400, L4 10^2=100
__device__ __forceinline__ int level_base(int lvl) {
    switch (lvl) {
        case 0:  return 0;
        case 1:  return 25600;
        case 2:  return 32000;
        case 3:  return 33600;
        default: return 34000;
    }
}

// ---------------------------------------------------------------- kernel A
__global__ __launch_bounds__(256) void init_winner(unsigned long long* __restrict__ w) {
    const int i = blockIdx.x * 256 + threadIdx.x;
    if (i < TOTAL_PIX) w[i] = INIT_KEY;
}

// ---------------------------------------------------------------- kernel B
// one wave per (box, level) pair: rasterize the shrunk rect, atomicMin packed keys.
__global__ __launch_bounds__(256) void scatter_kernel(
    const float* __restrict__ gt,            // 128 x 5
    unsigned long long* __restrict__ w)      // 34100 winner keys
{
    const int gtid = blockIdx.x * 256 + threadIdx.x;
    const int pair = gtid >> 6;              // wave id = (box, level)
    const int lane = threadIdx.x & 63;
    if (pair >= MAX_BOXES * NLVL) return;
    const int box = pair & (MAX_BOXES - 1);
    const int lvl = pair >> 7;

    const float x1 = gt[box * 5 + 0];
    const float y1 = gt[box * 5 + 1];
    const float x2 = gt[box * 5 + 2];
    const float y2 = gt[box * 5 + 3];
    const bool valid = (fabsf(x1) > 0.f) || (fabsf(y1) > 0.f) ||
                       (fabsf(x2) > 0.f) || (fabsf(y2) > 0.f);
    if (!valid) return;                      // wave-uniform

    const float stride = (float)(8 << lvl);
    const float inv_s  = 1.0f / stride;      // exact pow2
    const int   fw     = 160 >> lvl;
    const float fwm1   = (float)(fw - 1);

    // shrink rect — identical op order to reference
    const float bx1 = x1 * inv_s, by1 = y1 * inv_s;
    const float bx2 = x2 * inv_s, by2 = y2 * inv_s;
    const float cx = (bx1 + bx2) * 0.5f;
    const float cy = (by1 + by2) * 0.5f;
    const float hw = ((bx2 - bx1) * 0.2f) * 0.5f;
    const float hh = ((by2 - by1) * 0.2f) * 0.5f;
    const int px1 = (int)fminf(fmaxf(floorf(cx - hw), 0.f), fwm1);
    const int py1 = (int)fminf(fmaxf(floorf(cy - hh), 0.f), fwm1);
    const int px2 = min(max((int)ceilf(cx + hw), px1 + 1), fw);
    const int py2 = min(max((int)ceilf(cy + hh), py1 + 1), fw);

    const int rw = px2 - px1;
    const int n  = rw * (py2 - py1);         // <= ~144 at level 0
    const int base = level_base(lvl);

    for (int i = lane; i < n; i += 64) {
        const int ry = i / rw;
        const int rx = i - ry * rw;
        const int gx = px1 + rx;
        const int gy = py1 + ry;
        const float sx = ((float)gx + 0.5f) * stride;
        const float sy = ((float)gy + 0.5f) * stride;
        // identical fp32 expressions as reference -> bit-exact area
        const float dl = fmaxf(sx - x1, 0.f);
        const float dt = fmaxf(sy - y1, 0.f);
        const float dr = fmaxf(x2 - sx, 0.f);
        const float db = fmaxf(y2 - sy, 0.f);
        const float area = (dl + dr) * (dt + db);
        // area >= 0 so float bits are order-preserving; low 32 bits = box idx
        // u64 min == lexicographic (area, idx) == argmin first-occurrence tie-break
        const unsigned long long key =
            ((unsigned long long)__float_as_uint(area) << 32) | (unsigned)box;
        atomicMin(&w[base + gy * fw + gx], key);
    }
}

// ---------------------------------------------------------------- kernel C
__global__ __launch_bounds__(256) void gather_kernel(
    const float* __restrict__ gt,
    const float* __restrict__ fsw,
    const unsigned long long* __restrict__ w,
    float* __restrict__ out_cls,             // 34100 x 82
    float* __restrict__ out_reg)             // 34100 x 6
{
    __shared__ float4 sbx[MAX_BOXES];
    __shared__ float  ssw[MAX_BOXES][NLVL];
    __shared__ int    slab[MAX_BOXES];
    __shared__ float  st_soft[PPB];
    __shared__ float  st_ispos[PPB];
    __shared__ int    st_lab[PPB];
    __shared__ float  st_reg[PPB][4];

    const int t = threadIdx.x;
    const int block_base = blockIdx.x * PPB;

    // stage boxes / labels / weights
    if (t < MAX_BOXES) {
        const float x1 = gt[t * 5 + 0];
        const float y1 = gt[t * 5 + 1];
        const float x2 = gt[t * 5 + 2];
        const float y2 = gt[t * 5 + 3];
        sbx[t]  = make_float4(x1, y1, x2, y2);
        slab[t] = (int)gt[t * 5 + 4];
    } else {
        const int b = t - MAX_BOXES;
        #pragma unroll
        for (int l = 0; l < NLVL; ++l) ssw[b][l] = fsw[b * NLVL + l];
    }
    __syncthreads();

    const int count = min(PPB, TOTAL_PIX - block_base);

    if (t < PPB && t < count) {
        const int pid = block_base + t;
        int lvl, fw, lp; float stride;
        if      (pid < 25600) { lvl = 0; fw = 160; lp = pid;         stride = 8.f;   }
        else if (pid < 32000) { lvl = 1; fw = 80;  lp = pid - 25600; stride = 16.f;  }
        else if (pid < 33600) { lvl = 2; fw = 40;  lp = pid - 32000; stride = 32.f;  }
        else if (pid < 34000) { lvl = 3; fw = 20;  lp = pid - 33600; stride = 64.f;  }
        else                  { lvl = 4; fw = 10;  lp = pid - 34000; stride = 128.f; }
        const int gy = lp / fw;
        const int gx = lp - gy * fw;
        const float sx = ((float)gx + 0.5f) * stride;
        const float sy = ((float)gy + 0.5f) * stride;

        const unsigned long long key = w[pid];
        const bool pos = key < INIT_KEY;     // any touched pixel has smaller key
        const int  win = (int)(unsigned)key; // low 32 bits; 0 when untouched

        const float4 b = sbx[win];
        const float dl = fmaxf(sx - b.x, 0.f);
        const float dt = fmaxf(sy - b.y, 0.f);
        const float dr = fmaxf(b.z - sx, 0.f);
        const float db = fmaxf(b.w - sy, 0.f);

        const float is_pos = pos ? 1.0f : 0.0f;
        const float num = fminf(dl, dr) * fminf(dt, db);
        const float den = fmaxf(dl, dr) * fmaxf(dt, db);
        const float ap  = (den > 0.f) ? num / fmaxf(den, 1e-12f) : 0.0f;
        const float soft = pos ? ap * ssw[win][lvl] : 1.0f;

        const float rs = 0.25f / stride;     // exact: 1/(4*stride)
        st_soft[t]  = soft;
        st_ispos[t] = is_pos;
        st_lab[t]   = slab[win];
        st_reg[t][0] = dl * rs * is_pos;
        st_reg[t][1] = dt * rs * is_pos;
        st_reg[t][2] = dr * rs * is_pos;
        st_reg[t][3] = db * rs * is_pos;
    }
    __syncthreads();

    // coalesced writes of the block's contiguous output region
    if (count == PPB) {
        float4* cp = (float4*)(out_cls + (size_t)block_base * (NUM_CLS + 2));
        for (int q = t; q < PPB * (NUM_CLS + 2) / 4; q += 256) {   // 2624
            const int flat = q * 4;
            const int row0 = (int)((unsigned)flat / 82u);
            const int col0 = flat - row0 * 82;
            float v[4];
            #pragma unroll
            for (int k = 0; k < 4; ++k) {
                int r = row0, c = col0 + k;
                if (c >= 82) { c -= 82; ++r; }
                const float ip = st_ispos[r];
                float val;
                if (c < NUM_CLS)       val = (c == st_lab[r] && ip != 0.f) ? 1.0f : 0.0f;
                else if (c == NUM_CLS) val = st_soft[r];
                else                   val = ip;
                v[k] = val;
            }
            cp[q] = make_float4(v[0], v[1], v[2], v[3]);
        }
        float4* rp = (float4*)(out_reg + (size_t)block_base * 6);
        for (int q = t; q < PPB * 6 / 4; q += 256) {               // 192
            const int flat = q * 4;
            const int row0 = (int)((unsigned)flat / 6u);
            const int col0 = flat - row0 * 6;
            float v[4];
            #pragma unroll
            for (int k = 0; k < 4; ++k) {
                int r = row0, c = col0 + k;
                if (c >= 6) { c -= 6; ++r; }
                v[k] = (c < 4) ? st_reg[r][c] : ((c == 4) ? st_soft[r] : st_ispos[r]);
            }
            rp[q] = make_float4(v[0], v[1], v[2], v[3]);
        }
    } else {
        float* cbase = out_cls + (size_t)block_base * (NUM_CLS + 2);
        for (int q = t; q < count * (NUM_CLS + 2); q += 256) {
            const int r = (int)((unsigned)q / 82u);
            const int c = q - r * 82;
            const float ip = st_ispos[r];
            float val;
            if (c < NUM_CLS)       val = (c == st_lab[r] && ip != 0.f) ? 1.0f : 0.0f;
            else if (c == NUM_CLS) val = st_soft[r];
            else                   val = ip;
            cbase[q] = val;
        }
        float* rbase = out_reg + (size_t)block_base * 6;
        for (int q = t; q < count * 6; q += 256) {
            const int r = (int)((unsigned)q / 6u);
            const int c = q - r * 6;
            rbase[q] = (c < 4) ? st_reg[r][c] : ((c == 4) ? st_soft[r] : st_ispos[r]);
        }
    }
}

extern "C" void kernel_launch(void* const* d_in, const int* in_sizes, int n_in,
                              void* d_out, int out_size, void* d_ws, size_t ws_size,
                              hipStream_t stream) {
    (void)in_sizes; (void)n_in; (void)out_size; (void)ws_size;
    const float* gt  = (const float*)d_in[0];
    const float* fsw = (const float*)d_in[1];
    float* out_cls = (float*)d_out;
    float* out_reg = out_cls + (size_t)TOTAL_PIX * (NUM_CLS + 2);
    unsigned long long* w = (unsigned long long*)d_ws;   // needs 34100*8 = 272.8 KB

    init_winner  <<<(TOTAL_PIX + 255) / 256, 256, 0, stream>>>(w);
    scatter_kernel<<<(MAX_BOXES * NLVL * 64 + 255) / 256, 256, 0, stream>>>(gt, w);
    gather_kernel<<<(TOTAL_PIX + PPB - 1) / PPB, 256, 0, stream>>>(gt, fsw, w, out_cls, out_reg);
}